// Round 1
// baseline (81.194 us; speedup 1.0000x reference)
//
#include <hip/hip_runtime.h>

#define NIN 5
#define POL 55

// Parse E (DFS-ordered exponent table, 55x5, deg 1..3) + layer/omegas/filter
// into a canonical coefficient layout in workspace:
//   w[0..4]   A_j        (degree-1 coefs)
//   w[5..19]  B_{j<=k}   (degree-2, triangular order)
//   w[20..54] C_{j<=k<=l}(degree-3, triangular order)
//   w[55..59] cos coefs (layer[55..59])
//   w[60..64] sin coefs (layer[60..64])
//   w[65]=omegas[0]  w[66]=omegas[1]  w[67]=filt[0]  w[68]=filt[1]
__global__ void prep_kernel(const float* __restrict__ layer,
                            const float* __restrict__ omegas,
                            const float* __restrict__ ext_filter,
                            const int* __restrict__ E,
                            float* __restrict__ w) {
    int k = threadIdx.x;
    if (k < POL) {
        int e[NIN], d = 0;
        #pragma unroll
        for (int j = 0; j < NIN; ++j) { e[j] = E[k * NIN + j]; d += e[j]; }
        // expand exponents into sorted variable multiset (size d <= 3)
        int vars[3] = {0, 0, 0};
        int c = 0;
        for (int j = 0; j < NIN; ++j)
            for (int r = 0; r < e[j]; ++r) vars[c++] = j;
        int slot;
        if (d == 1) {
            slot = vars[0];
        } else if (d == 2) {
            int j = vars[0], kk = vars[1];
            slot = 5 + j * NIN - j * (j - 1) / 2 + (kk - j);
        } else {
            const int base3[5] = {0, 15, 25, 31, 34};
            int j = vars[0], kk = vars[1], l = vars[2];
            int m = NIN - j;
            int a = kk - j;
            slot = 20 + base3[j] + a * m - a * (a - 1) / 2 + (l - kk);
        }
        w[slot] = layer[k];
    } else if (k < POL + 10) {
        w[k] = layer[k];            // trig coefficients pass through
    } else if (k == POL + 10) {
        w[65] = omegas[0];
        w[66] = omegas[1];
        w[67] = ext_filter[0];
        w[68] = ext_filter[1];
    }
}

__global__ __launch_bounds__(256) void main_kernel(
    const float4* __restrict__ x,
    const float* __restrict__ t,
    const float* __restrict__ w,
    float2* __restrict__ out,
    int n) {
    int i = blockIdx.x * blockDim.x + threadIdx.x;
    if (i >= n) return;

    float4 xv = x[i];
    float tv = t[i];
    float v[NIN] = {xv.x, xv.y, xv.z, xv.w, tv};

    // s = sum_j v_j * ( A_j + sum_{k>=j} v_k * ( B_jk + sum_{l>=k} C_jkl v_l ) )
    float s = 0.f;
    int i2 = 5, i3 = 20;
    #pragma unroll
    for (int j = 0; j < NIN; ++j) {
        float qj = 0.f;
        #pragma unroll
        for (int k = j; k < NIN; ++k) {
            float r = w[i2++];
            #pragma unroll
            for (int l = k; l < NIN; ++l) r = fmaf(w[i3++], v[l], r);
            qj = fmaf(r, v[k], qj);
        }
        s = fmaf(v[j], w[j] + qj, s);
    }

    float w0 = w[65], w1 = w[66];
    #pragma unroll
    for (int j = 0; j < NIN; ++j) {
        s = fmaf(w[55 + j], __cosf(w0 * v[j]), s);
        s = fmaf(w[60 + j], __sinf(w1 * v[j]), s);
    }

    out[i] = make_float2(s * w[67], s * w[68]);
}

extern "C" void kernel_launch(void* const* d_in, const int* in_sizes, int n_in,
                              void* d_out, int out_size, void* d_ws, size_t ws_size,
                              hipStream_t stream) {
    const float* x          = (const float*)d_in[0];
    const float* t          = (const float*)d_in[1];
    const float* layer      = (const float*)d_in[2];
    const float* omegas     = (const float*)d_in[3];
    const float* ext_filter = (const float*)d_in[4];
    const int*   E          = (const int*)d_in[5];
    float* w = (float*)d_ws;

    int n = in_sizes[0] / 4;  // NSTATES = 4

    prep_kernel<<<1, 128, 0, stream>>>(layer, omegas, ext_filter, E, w);
    main_kernel<<<(n + 255) / 256, 256, 0, stream>>>(
        (const float4*)x, t, w, (float2*)d_out, n);
}

// Round 2
// 79.699 us; speedup vs baseline: 1.0188x; 1.0188x over previous
//
#include <hip/hip_runtime.h>

#define NIN 5
#define POL 55

// Single fused kernel. Each block parses the coefficient tables into LDS
// (redundantly, ~1.4 KB of L2-broadcast reads per block), then evaluates the
// triangular polynomial + trig library for 4 rows per thread.
//
// LDS layout:
//   w[0..4]   A_j        (degree-1 coefs)
//   w[5..19]  B_{j<=k}   (degree-2, triangular order)
//   w[20..54] C_{j<=k<=l}(degree-3, triangular order)
//   w[55..59] cos coefs  (layer[55..59])
//   w[60..64] sin coefs  (layer[60..64])
//   w[65]=omegas[0]  w[66]=omegas[1]  w[67]=filt[0]  w[68]=filt[1]
__global__ __launch_bounds__(256) void fused_kernel(
    const float4* __restrict__ x,     // N rows of 4 states
    const float4* __restrict__ t4,    // N/4 packed time values
    const float* __restrict__ layer,
    const float* __restrict__ omegas,
    const float* __restrict__ ext_filter,
    const int* __restrict__ E,
    float4* __restrict__ out4,        // N/2 float4 (= N float2 rows)
    int n4) {
    __shared__ float w[69];
    int k = threadIdx.x;
    if (k < POL) {
        int e[NIN];
        int d = 0;
        #pragma unroll
        for (int j = 0; j < NIN; ++j) { e[j] = E[k * NIN + j]; d += e[j]; }
        // expand exponents into sorted variable multiset (size d <= 3)
        int vars[3] = {0, 0, 0};
        int c = 0;
        for (int j = 0; j < NIN; ++j)
            for (int r = 0; r < e[j]; ++r) vars[c++] = j;
        int slot;
        if (d == 1) {
            slot = vars[0];
        } else if (d == 2) {
            int j = vars[0], kk = vars[1];
            slot = 5 + j * NIN - j * (j - 1) / 2 + (kk - j);
        } else {
            const int base3[5] = {0, 15, 25, 31, 34};
            int j = vars[0], kk = vars[1], l = vars[2];
            int m = NIN - j;
            int a = kk - j;
            slot = 20 + base3[j] + a * m - a * (a - 1) / 2 + (l - kk);
        }
        w[slot] = layer[k];
    } else if (k < POL + 10) {
        w[k] = layer[k];              // trig coefficients pass through
    } else if (k == POL + 10) {
        w[65] = omegas[0];
        w[66] = omegas[1];
        w[67] = ext_filter[0];
        w[68] = ext_filter[1];
    }
    __syncthreads();

    int i = blockIdx.x * blockDim.x + threadIdx.x;
    if (i >= n4) return;

    float4 tv = t4[i];
    float ts[4] = {tv.x, tv.y, tv.z, tv.w};
    float w0 = w[65], w1 = w[66];
    float f0 = w[67], f1 = w[68];
    float res[4];

    #pragma unroll
    for (int r = 0; r < 4; ++r) {
        float4 xv = x[i * 4 + r];
        float v[NIN] = {xv.x, xv.y, xv.z, xv.w, ts[r]};

        // s = sum_j v_j * ( A_j + sum_{k>=j} v_k * ( B_jk + sum_{l>=k} C_jkl v_l ) )
        float s = 0.f;
        int i2 = 5, i3 = 20;
        #pragma unroll
        for (int j = 0; j < NIN; ++j) {
            float qj = 0.f;
            #pragma unroll
            for (int kk = j; kk < NIN; ++kk) {
                float rr = w[i2++];
                #pragma unroll
                for (int l = kk; l < NIN; ++l) rr = fmaf(w[i3++], v[l], rr);
                qj = fmaf(rr, v[kk], qj);
            }
            s = fmaf(v[j], w[j] + qj, s);
        }

        #pragma unroll
        for (int j = 0; j < NIN; ++j) {
            s = fmaf(w[55 + j], __cosf(w0 * v[j]), s);
            s = fmaf(w[60 + j], __sinf(w1 * v[j]), s);
        }
        res[r] = s;
    }

    out4[2 * i]     = make_float4(res[0] * f0, res[0] * f1, res[1] * f0, res[1] * f1);
    out4[2 * i + 1] = make_float4(res[2] * f0, res[2] * f1, res[3] * f0, res[3] * f1);
}

extern "C" void kernel_launch(void* const* d_in, const int* in_sizes, int n_in,
                              void* d_out, int out_size, void* d_ws, size_t ws_size,
                              hipStream_t stream) {
    const float* x          = (const float*)d_in[0];
    const float* t          = (const float*)d_in[1];
    const float* layer      = (const float*)d_in[2];
    const float* omegas     = (const float*)d_in[3];
    const float* ext_filter = (const float*)d_in[4];
    const int*   E          = (const int*)d_in[5];

    int n = in_sizes[1];      // N_DATA (t has one element per row)
    int n4 = n / 4;           // N_DATA = 1e6, divisible by 4

    fused_kernel<<<(n4 + 255) / 256, 256, 0, stream>>>(
        (const float4*)x, (const float4*)t, layer, omegas, ext_filter, E,
        (float4*)d_out, n4);
}

// Round 3
// 79.531 us; speedup vs baseline: 1.0209x; 1.0021x over previous
//
#include <hip/hip_runtime.h>

#define NIN 5
#define POL 55
#define ROWS_PER_THREAD 4
#define BLOCK 256
#define TILE (BLOCK * ROWS_PER_THREAD)

// Single fused kernel. Each block parses the coefficient tables into LDS
// (redundantly, ~1.4 KB of L2-broadcast reads per block), then evaluates the
// triangular polynomial + trig library for 4 rows per thread with perfect
// per-instruction coalescing (row = base + r*256 + tid).
//
// LDS layout:
//   w[0..4]   A_j        (degree-1 coefs)
//   w[5..19]  B_{j<=k}   (degree-2, triangular order)
//   w[20..54] C_{j<=k<=l}(degree-3, triangular order)
//   w[55..59] cos coefs  (layer[55..59])
//   w[60..64] sin coefs  (layer[60..64])
//   w[65]=omegas[0]  w[66]=omegas[1]  w[67]=filt[0]  w[68]=filt[1]
__global__ __launch_bounds__(BLOCK) void fused_kernel(
    const float4* __restrict__ x,     // N rows of 4 states
    const float* __restrict__ t,      // N time values
    const float* __restrict__ layer,
    const float* __restrict__ omegas,
    const float* __restrict__ ext_filter,
    const int* __restrict__ E,
    float2* __restrict__ out,         // N float2 rows
    int n) {
    __shared__ float w[69];
    int k = threadIdx.x;
    if (k < POL) {
        int e[NIN];
        int d = 0;
        #pragma unroll
        for (int j = 0; j < NIN; ++j) { e[j] = E[k * NIN + j]; d += e[j]; }
        // expand exponents into sorted variable multiset (size d <= 3)
        int vars[3] = {0, 0, 0};
        int c = 0;
        for (int j = 0; j < NIN; ++j)
            for (int r = 0; r < e[j]; ++r) vars[c++] = j;
        int slot;
        if (d == 1) {
            slot = vars[0];
        } else if (d == 2) {
            int j = vars[0], kk = vars[1];
            slot = 5 + j * NIN - j * (j - 1) / 2 + (kk - j);
        } else {
            const int base3[5] = {0, 15, 25, 31, 34};
            int j = vars[0], kk = vars[1], l = vars[2];
            int m = NIN - j;
            int a = kk - j;
            slot = 20 + base3[j] + a * m - a * (a - 1) / 2 + (l - kk);
        }
        w[slot] = layer[k];
    } else if (k < POL + 10) {
        w[k] = layer[k];              // trig coefficients pass through
    } else if (k == POL + 10) {
        w[65] = omegas[0];
        w[66] = omegas[1];
        w[67] = ext_filter[0];
        w[68] = ext_filter[1];
    }
    __syncthreads();

    int base = blockIdx.x * TILE + threadIdx.x;
    float w0 = w[65], w1 = w[66];
    float f0 = w[67], f1 = w[68];

    #pragma unroll
    for (int r = 0; r < ROWS_PER_THREAD; ++r) {
        int row = base + r * BLOCK;
        if (row >= n) break;

        float4 xv = x[row];
        float tv = t[row];
        float v[NIN] = {xv.x, xv.y, xv.z, xv.w, tv};

        // s = sum_j v_j * ( A_j + sum_{k>=j} v_k * ( B_jk + sum_{l>=k} C_jkl v_l ) )
        float s = 0.f;
        int i2 = 5, i3 = 20;
        #pragma unroll
        for (int j = 0; j < NIN; ++j) {
            float qj = 0.f;
            #pragma unroll
            for (int kk = j; kk < NIN; ++kk) {
                float rr = w[i2++];
                #pragma unroll
                for (int l = kk; l < NIN; ++l) rr = fmaf(w[i3++], v[l], rr);
                qj = fmaf(rr, v[kk], qj);
            }
            s = fmaf(v[j], w[j] + qj, s);
        }

        #pragma unroll
        for (int j = 0; j < NIN; ++j) {
            s = fmaf(w[55 + j], __cosf(w0 * v[j]), s);
            s = fmaf(w[60 + j], __sinf(w1 * v[j]), s);
        }

        out[row] = make_float2(s * f0, s * f1);
    }
}

extern "C" void kernel_launch(void* const* d_in, const int* in_sizes, int n_in,
                              void* d_out, int out_size, void* d_ws, size_t ws_size,
                              hipStream_t stream) {
    const float* x          = (const float*)d_in[0];
    const float* t          = (const float*)d_in[1];
    const float* layer      = (const float*)d_in[2];
    const float* omegas     = (const float*)d_in[3];
    const float* ext_filter = (const float*)d_in[4];
    const int*   E          = (const int*)d_in[5];

    int n = in_sizes[1];      // N_DATA (t has one element per row)

    fused_kernel<<<(n + TILE - 1) / TILE, BLOCK, 0, stream>>>(
        (const float4*)x, t, layer, omegas, ext_filter, E,
        (float2*)d_out, n);
}